// Round 10
// baseline (771.208 us; speedup 1.0000x reference)
//
#include <hip/hip_runtime.h>
#include <hip/hip_bf16.h>
#include <hip/hip_fp16.h>

// ---------------------------------------------------------------------------
// RPN: conv3x3(512->512)+ReLU, then 1x1 heads (18ch cls, 36ch bbox)
// B=16, C=512, H=50, W=76
// Strategy: fp16 MFMA implicit GEMM over padded NHWC.
// R1: bijective XCD-aware block swizzle on conv grid.
// R2: fp16 inputs (8x less rounding error than bf16, same MFMA rate).
// R3: targeted halo-border zero instead of full-buffer memset.
// R4: LDS-staged transposed conv epilogue -> coalesced 512B C-stores.
// R5: heads split into 2 block groups (27 outs each) -> 2 waves/SIMD.
// R6: ws_size-checked exact fallback path.
// R7: dy-fused A staging (A staged once per (dy,kc), shared by 3 dx taps).
// R8: staged-A source clamp + A_ROWS 136->134 (j<=133 only).
// R9: front-end fused into ONE dispatch (pad-transpose + border-zero +
//     weight-convert as block-role ranges) - removes 2 launch gaps, lets
//     the tiny roles fill CUs alongside the transpose. Conv/heads untouched.
// ---------------------------------------------------------------------------

typedef __attribute__((ext_vector_type(4))) float f32x4;
typedef __attribute__((ext_vector_type(8))) short s16x8;

#define BATCH 16
#define CIN   512
#define HH    50
#define WW    76
#define HP    52
#define WPAD  78
#define SPATIAL 3800                 // H*W
#define MTOT  60800                  // B*H*W
#define PAD_Y_STRIDE (WPAD*CIN)      // 39936 elems
#define PAD_B_STRIDE (HP*PAD_Y_STRIDE) // 2076672 elems
#define PAD_ELEMS (BATCH*PAD_B_STRIDE) // 33226752 shorts
#define PAD_BYTES (PAD_ELEMS*2)        // 66453504 bytes
#define WB_ELEMS (9*512*512)         // 2359296 shorts
#define WS_NEEDED (PAD_BYTES + (size_t)WB_ELEMS*2)  // 71172096 bytes
#define WB_TAP_STRIDE (512*512)      // 262144 elems
#define OUT_FEAT_ELEMS (MTOT*512)    // 31129600
#define OUT_CLS_OFF  OUT_FEAT_ELEMS
#define OUT_BBOX_OFF (OUT_FEAT_ELEMS + MTOT*18)

#define MTILES_PER_IMG 30            // 29 full + 1 partial (88 valid rows)
#define CONV_GRID (16 * MTILES_PER_IMG * 4)   // 1920 blocks (divisible by 8)
#define A_ROWS 134                   // fragments read j0+dx <= 131+2 = 133
#define A_CHUNKS (A_ROWS * 8)        // 1072 16B chunks
#define LDSA_BYTES (A_CHUNKS * 16)   // 17152
#define A_CLAMP (PAD_ELEMS - 8)      // per-lane source clamp (hygiene)
#define CSTRIDE 132                  // C-stage row stride (floats)

// fused front-end block-role ranges
#define PAD_BLOCKS 12800             // 16*50*2*8
#define BORDER_BLOCKS 1024
#define WCONV_BLOCKS 1024
#define FRONT_GRID (PAD_BLOCKS + BORDER_BLOCKS + WCONV_BLOCKS)  // 14848

#define GLOAD16(gp, lp) __builtin_amdgcn_global_load_lds( \
    (const __attribute__((address_space(1))) void*)(gp),  \
    (__attribute__((address_space(3))) void*)(lp), 16, 0, 0)

// fp32 -> fp16 (RNE), bit pattern as short for packed LDS/MFMA use
__device__ __forceinline__ short f2h(float f) {
  return (short)__half_as_short(__float2half(f));
}

// ---------------------------------------------------------------------------
// Kernel 1 (fused front-end), three block-uniform roles:
//   blocks [0, 12800):        NCHW fp32 -> padded NHWC fp16 transpose
//   blocks [12800, 13824):    zero the pad-buffer halo border
//   blocks [13824, 14848):    W_conv fp32 [co][ci][3][3] -> fp16 wb[tap][co][ci]
// ---------------------------------------------------------------------------
__global__ __launch_bounds__(256) void front_kernel(const float* __restrict__ in,
                                                    const float* __restrict__ w,
                                                    short* __restrict__ pad,
                                                    short* __restrict__ wb) {
  __shared__ short tile[64][65];  // pad role only; +1 col vs bank conflicts
  const int bi = blockIdx.x;
  const int t = threadIdx.x;

  if (bi < PAD_BLOCKS) {
    // ---- pad/transpose role ----
    int ct = bi & 7;
    int xt = (bi >> 3) & 1;
    int by = bi >> 4;              // 0..799
    int y  = by % 50;
    int b  = by / 50;
    int c0 = ct * 64, x0 = xt * 64;
    #pragma unroll
    for (int i = 0; i < 16; ++i) {
      int idx = t + i * 256;
      int c_l = idx >> 6, x_l = idx & 63;
      int x = x0 + x_l;
      float v = 0.f;
      if (x < WW) v = in[(b * 512 + c0 + c_l) * SPATIAL + y * WW + x];
      tile[x_l][c_l] = f2h(v);
    }
    __syncthreads();
    int x_l = t >> 2, cg = (t & 3) * 16;
    int x = x0 + x_l;
    if (x < WW) {
      short* dst = &pad[b * PAD_B_STRIDE + (y + 1) * PAD_Y_STRIDE +
                        (x + 1) * CIN + c0 + cg];
      union { short s[16]; int4 v[2]; } u;
      #pragma unroll
      for (int j = 0; j < 16; ++j) u.s[j] = tile[x_l][cg + j];
      *(int4*)dst = u.v[0];
      *((int4*)dst + 1) = u.v[1];
    }
  } else if (bi < PAD_BLOCKS + BORDER_BLOCKS) {
    // ---- halo-border zero role ----
    // Per image: rows y=0,51 (2*4992 int4-chunks) + cols x=0,77 for y=1..50
    // (50*128 chunks) = 16384 = 2^14 chunks.
    int g = (bi - PAD_BLOCKS) * 256 + t;      // 0..262143
    int img = g >> 14;
    int e8 = g & 16383;
    int dst;
    if (e8 < 9984) {                          // full top/bottom rows
      int row_sel = e8 / 4992;                // 0 or 1
      int off = (e8 - row_sel * 4992) * 8;    // 0..39928
      dst = img * PAD_B_STRIDE + row_sel * 51 * PAD_Y_STRIDE + off;
    } else {                                  // left/right columns, y=1..50
      int f8 = e8 - 9984;                     // 0..6399
      int y = 1 + (f8 >> 7);
      int side = (f8 >> 6) & 1;
      int c8 = (f8 & 63) * 8;
      dst = img * PAD_B_STRIDE + y * PAD_Y_STRIDE + (side ? 77 * 512 : 0) + c8;
    }
    *(int4*)&pad[dst] = make_int4(0, 0, 0, 0);
  } else {
    // ---- weight-convert role ----
    int g = (bi - PAD_BLOCKS - BORDER_BLOCKS) * 256 + t;  // 0..262143 = co*512+ci
    const float* src = w + g * 9;
    #pragma unroll
    for (int tap = 0; tap < 9; ++tap)
      wb[tap * WB_TAP_STRIDE + g] = f2h(src[tap]);
  }
}

// ---------------------------------------------------------------------------
// Kernel 2: conv3x3 + ReLU, dy-fused implicit GEMM.
// Loop dy(3) -> kc(8) -> dx(3): A (134 rows x 64k) staged once per (dy,kc),
// read by all 3 dx at LDS row offset +dx. B staged per sub-phase (16 KB).
// 2-barrier-per-subphase structure preserved (72 subphases).
// grid = 480 m-tiles * 4 nt; per-image tiling (mtl in [0,30)).
// Staged A window can exceed the image block on the last tile (flat row up
// to 4097 > 4056); those rows feed only discarded outputs (valid outputs
// read j <= 91 there) and sources are clamped to stay inside the pad buffer.
// ---------------------------------------------------------------------------
__global__ __launch_bounds__(256) void conv_mfma(const short* __restrict__ padin,
                                                 const short* __restrict__ wb,
                                                 float* __restrict__ out) {
  __shared__ __align__(16) char smem[64 * CSTRIDE * 4];  // 33792 B
  short* ldsA = (short*)smem;                    // 17152 B (1072 chunks)
  short* ldsB = (short*)(smem + LDSA_BYTES);     // 16384 B
  float* clds = (float*)smem;                    // epilogue overlay
  const int t = threadIdx.x;
  const int w = t >> 6;
  const int l = t & 63;

  // --- XCD swizzle: nwg=1920, q=240, r=0 -> logical = xcd*240 + idx ---
  const int orig = blockIdx.x;
  const int xcd = orig & 7;
  const int idx = orig >> 3;
  const int q = CONV_GRID >> 3, r = CONV_GRID & 7;
  const int logical = (xcd < r ? xcd * (q + 1) : r * (q + 1) + (xcd - r) * q) + idx;
  const int nt = logical & 3;
  const int mt = logical >> 2;          // 0..479
  const int img = mt / MTILES_PER_IMG;
  const int mtl = mt - img * MTILES_PER_IMG;
  const int off0 = mtl * 128;           // first output row (local) of tile
  const int y0 = off0 / 76;
  const int x0 = off0 - y0 * 76;
  const int baseA = img * PAD_B_STRIDE + y0 * PAD_Y_STRIDE + x0 * CIN;
  const int wm = w >> 1, wn = w & 1;

  // A staging: chunk c in [0,1072): row j=c>>3, k-octet kb=c&7.
  int aglb[4], boffs[4];
  #pragma unroll
  for (int i = 0; i < 4; ++i) {
    int c = t + i * 256;
    aglb[i] = (c >> 3) * CIN + (c & 7) * 8;
    boffs[i] = (nt * 128 + (c >> 3)) * 512 + (c & 7) * 8;
  }
  const int aglb4 = (128 + (t >> 3)) * CIN + (t & 7) * 8;  // rows 128..133

  // fragment rows: A row j0 = m_local + 2*wraps (dx added at read time)
  int arow[4], brow[4];
  #pragma unroll
  for (int i = 0; i < 4; ++i) {
    const int m_l = wm * 64 + i * 16 + (l & 15);
    const int j0 = m_l + 2 * ((x0 + m_l) / 76);
    arow[i] = j0 * 64 + (l >> 4) * 8;
    brow[i] = (wn * 64 + i * 16 + (l & 15)) * 64 + (l >> 4) * 8;
  }

  f32x4 acc[4][4];
  #pragma unroll
  for (int a = 0; a < 4; ++a)
    #pragma unroll
    for (int b = 0; b < 4; ++b)
      acc[a][b] = (f32x4)(0.f);

  #pragma unroll 1
  for (int dy = 0; dy < 3; ++dy) {
    const int abase_dy = baseA + dy * PAD_Y_STRIDE;
    #pragma unroll 1
    for (int kc = 0; kc < 8; ++kc) {
      const int ko = kc * 64;
      #pragma unroll
      for (int dx = 0; dx < 3; ++dx) {
        if (dx == 0) {   // stage A once per (dy,kc): 1072 chunks
          #pragma unroll
          for (int i = 0; i < 4; ++i) {
            int ga = abase_dy + ko + aglb[i];
            ga = ga < A_CLAMP ? ga : A_CLAMP;      // last-tile hygiene
            GLOAD16(padin + ga, &ldsA[(t + i * 256) * 8]);
          }
          if (t < 48) {
            int ga = abase_dy + ko + aglb4;
            ga = ga < A_CLAMP ? ga : A_CLAMP;
            GLOAD16(padin + ga, &ldsA[(1024 + t) * 8]);
          }
        }
        const int boff_t = (dy * 3 + dx) * WB_TAP_STRIDE;
        #pragma unroll
        for (int i = 0; i < 4; ++i)
          GLOAD16(wb + boffs[i] + boff_t + ko, &ldsB[(t + i * 256) * 8]);
        __syncthreads();   // drains vmcnt (global_load_lds) + lgkmcnt
        #pragma unroll
        for (int kk = 0; kk < 2; ++kk) {
          s16x8 av[4], bv[4];
          #pragma unroll
          for (int i = 0; i < 4; ++i)
            av[i] = *(const s16x8*)&ldsA[arow[i] + dx * 64 + kk * 32];
          #pragma unroll
          for (int i = 0; i < 4; ++i)
            bv[i] = *(const s16x8*)&ldsB[brow[i] + kk * 32];
          #pragma unroll
          for (int a = 0; a < 4; ++a)
            #pragma unroll
            for (int b = 0; b < 4; ++b)
              acc[a][b] = __builtin_amdgcn_mfma_f32_16x16x32_f16(av[a], bv[b],
                                                                 acc[a][b], 0, 0, 0);
        }
        __syncthreads();
      }
    }
  }

  // ---- epilogue: ReLU + LDS transpose stage -> coalesced NCHW stores ----
  // acc[a][b]: m_local = wm*64+a*16+(l>>4)*4+j, co_local = wn*64+b*16+(l&15)
  #pragma unroll
  for (int ph = 0; ph < 2; ++ph) {
    __syncthreads();          // LDS free (prev phase readout / K-loop done)
    #pragma unroll
    for (int bb = 0; bb < 2; ++bb) {
      const int b = 2 * ph + bb;
      const int n64 = wn * 32 + bb * 16 + (l & 15);
      #pragma unroll
      for (int a = 0; a < 4; ++a) {
        const int m_local = wm * 64 + a * 16 + (l >> 4) * 4;
        f32x4 v = acc[a][b];
        #pragma unroll
        for (int j = 0; j < 4; ++j) v[j] = fmaxf(v[j], 0.f);
        *(f32x4*)&clds[n64 * CSTRIDE + m_local] = v;
      }
    }
    __syncthreads();
    #pragma unroll
    for (int i = 0; i < 8; ++i) {
      const int c2 = t + i * 256;          // 0..2047
      const int n64 = c2 >> 5;             // 0..63
      const int m0 = (c2 & 31) * 4;        // 0..124
      const int ml = mtl * 128 + m0;       // local spatial (aligned to 4)
      if (ml < SPATIAL) {                  // partial-tile guard (3800%4==0)
        f32x4 v = *(const f32x4*)&clds[n64 * CSTRIDE + m0];
        const int co = nt * 128 + (n64 >> 5) * 64 + ph * 32 + (n64 & 31);
        *(f32x4*)&out[(img * 512 + co) * SPATIAL + ml] = v;
      }
    }
  }
}

// ---------------------------------------------------------------------------
// Fallback conv (only if ws_size < WS_NEEDED): direct fp32 conv + ReLU.
// ---------------------------------------------------------------------------
__global__ __launch_bounds__(256) void conv_fallback(const float* __restrict__ in,
                                                     const float* __restrict__ w,
                                                     float* __restrict__ out) {
  int g = blockIdx.x * 256 + threadIdx.x;     // 0..31129599
  int bc = g / SPATIAL;                        // b*512 + co
  int sp = g - bc * SPATIAL;
  int b = bc >> 9, co = bc & 511;
  int y = sp / WW, x = sp - y * WW;
  const float* ib = in + (b * 512) * SPATIAL;
  const float* wc = w + co * 512 * 9;
  float s = 0.f;
  for (int ci = 0; ci < 512; ++ci) {
    const float* ip = ib + ci * SPATIAL;
    const float* wp = wc + ci * 9;
    #pragma unroll
    for (int dy = 0; dy < 3; ++dy) {
      int yy = y + dy - 1;
      if (yy < 0 || yy >= HH) continue;
      #pragma unroll
      for (int dx = 0; dx < 3; ++dx) {
        int xx = x + dx - 1;
        if (xx < 0 || xx >= WW) continue;
        s += ip[yy * WW + xx] * wp[dy * 3 + dx];
      }
    }
  }
  out[g] = fmaxf(s, 0.f);
}

// ---------------------------------------------------------------------------
// Kernel 3: 1x1 heads, fp32 VALU. One thread per spatial position.
// Two block groups: group 0 -> 18 cls + bbox 0..8, group 1 -> bbox 9..35.
// ---------------------------------------------------------------------------
__global__ __launch_bounds__(256) void heads_kernel(
    const float* __restrict__ feat, const float* __restrict__ wc,
    const float* __restrict__ bc, const float* __restrict__ wbx,
    const float* __restrict__ bbx, float* __restrict__ out) {
  const int sel = blockIdx.x >= 238;               // block-uniform
  const int bid = blockIdx.x - (sel ? 238 : 0);
  int g = bid * 256 + threadIdx.x;
  if (g >= MTOT) return;
  int b = g / 3800;
  int sp = g - b * 3800;
  const float* f0 = feat + b * 512 * SPATIAL + sp;
  float fcur[8], fnext[8];
  #pragma unroll
  for (int u = 0; u < 8; ++u) fcur[u] = f0[u * SPATIAL];

  float acc[27];
  if (sel == 0) {
    #pragma unroll
    for (int o = 0; o < 18; ++o) acc[o] = bc[o];
    #pragma unroll
    for (int o = 0; o < 9; ++o) acc[18 + o] = bbx[o];
    #pragma unroll 1
    for (int c8 = 0; c8 < 64; ++c8) {
      if (c8 < 63) {
        #pragma unroll
        for (int u = 0; u < 8; ++u) fnext[u] = f0[((c8 + 1) * 8 + u) * SPATIAL];
      }
      #pragma unroll
      for (int u = 0; u < 8; ++u) {
        int ci = c8 * 8 + u;
        #pragma unroll
        for (int o = 0; o < 18; ++o) acc[o] += wc[o * 512 + ci] * fcur[u];
        #pragma unroll
        for (int o = 0; o < 9; ++o) acc[18 + o] += wbx[o * 512 + ci] * fcur[u];
      }
      #pragma unroll
      for (int u = 0; u < 8; ++u) fcur[u] = fnext[u];
    }
    float* oc = out + OUT_CLS_OFF;
    #pragma unroll
    for (int o = 0; o < 18; ++o) oc[(b * 18 + o) * 3800 + sp] = acc[o];
    float* ob = out + OUT_BBOX_OFF;
    #pragma unroll
    for (int o = 0; o < 9; ++o) ob[(b * 36 + o) * 3800 + sp] = acc[18 + o];
  } else {
    #pragma unroll
    for (int o = 0; o < 27; ++o) acc[o] = bbx[9 + o];
    #pragma unroll 1
    for (int c8 = 0; c8 < 64; ++c8) {
      if (c8 < 63) {
        #pragma unroll
        for (int u = 0; u < 8; ++u) fnext[u] = f0[((c8 + 1) * 8 + u) * SPATIAL];
      }
      #pragma unroll
      for (int u = 0; u < 8; ++u) {
        int ci = c8 * 8 + u;
        #pragma unroll
        for (int o = 0; o < 27; ++o) acc[o] += wbx[(9 + o) * 512 + ci] * fcur[u];
      }
      #pragma unroll
      for (int u = 0; u < 8; ++u) fcur[u] = fnext[u];
    }
    float* ob = out + OUT_BBOX_OFF;
    #pragma unroll
    for (int o = 0; o < 27; ++o) ob[(b * 36 + 9 + o) * 3800 + sp] = acc[o];
  }
}

// ---------------------------------------------------------------------------
extern "C" void kernel_launch(void* const* d_in, const int* in_sizes, int n_in,
                              void* d_out, int out_size, void* d_ws, size_t ws_size,
                              hipStream_t stream) {
  const float* features = (const float*)d_in[0];
  const float* W_conv   = (const float*)d_in[1];
  const float* W_cls    = (const float*)d_in[2];
  const float* b_cls    = (const float*)d_in[3];
  const float* W_bbox   = (const float*)d_in[4];
  const float* b_bbox   = (const float*)d_in[5];
  float* out = (float*)d_out;

  if (ws_size >= WS_NEEDED) {
    short* pad = (short*)d_ws;
    short* wb  = (short*)((char*)d_ws + PAD_BYTES);
    front_kernel<<<FRONT_GRID, 256, 0, stream>>>(features, W_conv, pad, wb);
    conv_mfma<<<CONV_GRID, 256, 0, stream>>>(pad, wb, out);
  } else {
    conv_fallback<<<OUT_FEAT_ELEMS / 256, 256, 0, stream>>>(features, W_conv, out);
  }
  heads_kernel<<<476, 256, 0, stream>>>(out, W_cls, b_cls, W_bbox, b_bbox, out);
}